// Round 4
// baseline (260.516 us; speedup 1.0000x reference)
//
#include <hip/hip_runtime.h>

// 2-layer tanh RNN, T=2048, B=2048, EMB=10, HID=8, NCLS=4, VOCAB=4.
// Time-chunking with 256-step warm-up (contraction rho^256 ~ 4e-3).
//
// R7 changes (from R6 post-mortem: halving per-wave issue work left per-step
// latency unchanged -> steps are latency-bound on a serial path; wall =
// steps x path-latency, extra waves only add contention. Arithmetic chain
// calibrates to ~250cy (R3 vs R5 delta: dep pk_fma ~12cy, tanh ~60cy);
// the other ~1000cy/step must be per-iteration memory waits (P ds_read and
// x global load both at use-distance 1):
//  1. Revert lane split: full chain per lane, 1024 waves = 1 wave/SIMD.
//  2. Distance-2 software pipeline: P-queue pq/nq/rq (ds_read issued 2 iters
//     before first use), x register queue x3/x4 (global load issued 2 iters
//     before its ds-address use). lgkm/vm waits now see long-completed loads.
//  3. Tree accumulators: L1 16-deep serial fma chain -> 4x 4-deep partials
//     + 3 pk_adds (h1->h1 path: 4 fma + 2 add + tanh); L0 split 4+4.
//     Layer skew (L1(t) || L0(t+1)) retained.

#define T_LEN 2048
#define B_LEN 2048
#define EMB_D 10
#define NCHUNK 32
#define CHUNK (T_LEN / NCHUNK)   // 64
#define WARM 256
#define KSCALE 2.8853900817779268f   // 2*log2(e)

typedef float v2f __attribute__((ext_vector_type(2)));

#define PINV(v) asm volatile("" : "+v"(v))
#define PINS(v) asm volatile("" : "+s"(v))

// pre is already scaled by 2*log2(e): tanh = 1 - 2/(2^pre + 1)
__device__ __forceinline__ float tanh_scaled(float pre) {
    float e = __builtin_amdgcn_exp2f(pre);
    float r = __builtin_amdgcn_rcpf(e + 1.0f);
    return __builtin_fmaf(-2.0f, r, 1.0f);
}
__device__ __forceinline__ v2f tanh2(v2f a) {
    v2f r; r.x = tanh_scaled(a.x); r.y = tanh_scaled(a.y); return r;
}
__device__ __forceinline__ v2f fma2(v2f a, v2f b, v2f c) {
    return __builtin_elementwise_fma(a, b, c);
}
__device__ __forceinline__ v2f mul2(v2f a, v2f b) { return a * b; }

__global__ void __launch_bounds__(64, 1)
rnn_fused(const int* __restrict__ x,
          const float* __restrict__ emb,
          const float* __restrict__ Wih0,
          const float* __restrict__ Whh0,
          const float* __restrict__ bih0,
          const float* __restrict__ bhh0,
          const float* __restrict__ Wih1,
          const float* __restrict__ Whh1,
          const float* __restrict__ bih1,
          const float* __restrict__ bhh1,
          const float* __restrict__ Wfc,
          const float* __restrict__ bfc,
          float* __restrict__ out)
{
    __shared__ __align__(16) float P[4][8];   // k-scaled pre-activation table, layer 0
    const int lane = threadIdx.x;
    if (lane < 32) {
        const int v = lane >> 3, l = lane & 7;
        float s = bih0[l] + bhh0[l];
        #pragma unroll
        for (int d = 0; d < EMB_D; ++d) s += Wih0[l * EMB_D + d] * emb[v * EMB_D + d];
        P[v][l] = s * KSCALE;
    }

    // Packed weights: wpk[p*8+j] = (W[2p][j], W[2p+1][j]) * KSCALE. Pinned in VGPRs.
    v2f whh0pk[32], wih1pk[32], whh1pk[32], b1pk[4];
    #pragma unroll
    for (int p = 0; p < 4; ++p)
        #pragma unroll
        for (int j = 0; j < 8; ++j) {
            v2f w;
            w.x = Whh0[(2 * p) * 8 + j] * KSCALE;
            w.y = Whh0[(2 * p + 1) * 8 + j] * KSCALE;
            PINV(w); whh0pk[p * 8 + j] = w;
        }
    #pragma unroll
    for (int p = 0; p < 4; ++p)
        #pragma unroll
        for (int j = 0; j < 8; ++j) {
            v2f w;
            w.x = Wih1[(2 * p) * 8 + j] * KSCALE;
            w.y = Wih1[(2 * p + 1) * 8 + j] * KSCALE;
            PINV(w); wih1pk[p * 8 + j] = w;
        }
    #pragma unroll
    for (int p = 0; p < 4; ++p)
        #pragma unroll
        for (int j = 0; j < 8; ++j) {
            v2f w;
            w.x = Whh1[(2 * p) * 8 + j] * KSCALE;
            w.y = Whh1[(2 * p + 1) * 8 + j] * KSCALE;
            PINV(w); whh1pk[p * 8 + j] = w;
        }
    #pragma unroll
    for (int p = 0; p < 4; ++p) {
        v2f w;
        w.x = (bih1[2 * p]     + bhh1[2 * p])     * KSCALE;
        w.y = (bih1[2 * p + 1] + bhh1[2 * p + 1]) * KSCALE;
        PINV(w); b1pk[p] = w;
    }

    // FC weights in SGPRs (wave-uniform; v_fma_f32 takes 1 SGPR operand).
    float wfc[32], bf[4];
    #pragma unroll
    for (int i = 0; i < 32; ++i) { wfc[i] = Wfc[i]; PINS(wfc[i]); }
    #pragma unroll
    for (int i = 0; i < 4; ++i)  { bf[i] = bfc[i]; PINS(bf[i]); }

    __syncthreads();

    const int tid = blockIdx.x * 64 + lane;
    const int b = tid & (B_LEN - 1);     // consecutive lanes -> consecutive b (coalesced)
    const int chunk = tid >> 11;         // uniform within a wave, 0..31
    const int t_begin = chunk * CHUNK;
    const int t_end = t_begin + CHUNK;
    int t_start = t_begin - WARM;
    if (t_start < 0) t_start = 0;        // chunk 0: exact initial state

    const v2f* __restrict__ Ppk = (const v2f*)&P[0][0];   // Ppk[v*4 + p]
    float4* __restrict__ outv = (float4*)out;
    const int tmax = t_end - 1;

    // Packed state: h0p[p] = (h0[2p], h0[2p+1]).
    v2f h0p[4], h1p[4];
    #pragma unroll
    for (int p = 0; p < 4; ++p) { h1p[p] = (v2f){0.f, 0.f}; }

    // ---- pipeline prologue ----
    // Invariant at top of iteration t:
    //   pq = P[x_{t+1}], nq = P[x_{t+2}]   (P-queue, ds_read 2 iters ahead)
    //   x3 = x_{t+3},    x4 = x_{t+4}      (x-queue, load 2 iters ahead)
    {
        int xa = x[t_start * B_LEN + b];
        #pragma unroll
        for (int p = 0; p < 4; ++p) h0p[p] = tanh2(Ppk[xa * 4 + p]);   // L0(ts), h_prev=0
    }
    int xb = x[(t_start + 1) * B_LEN + b];
    int xc = x[(t_start + 2) * B_LEN + b];
    v2f pq[4], nq[4];
    #pragma unroll
    for (int p = 0; p < 4; ++p) pq[p] = Ppk[xb * 4 + p];
    #pragma unroll
    for (int p = 0; p < 4; ++p) nq[p] = Ppk[xc * 4 + p];
    int x3 = x[(t_start + 3) * B_LEN + b];   // ts+3 <= 1987, in-bounds
    int x4 = x[(t_start + 4) * B_LEN + b];   // ts+4 <= 1988, in-bounds

    // ---- warm-up loop: iteration t computes L1(t), L0(t+1); no FC/store ----
    for (int t = t_start; t < t_begin; ++t) {
        int x5v = x[(t + 5) * B_LEN + b];    // t+5 <= t_begin+4 <= 1988, in-bounds
        v2f rq[4];
        #pragma unroll
        for (int p = 0; p < 4; ++p) rq[p] = Ppk[x3 * 4 + p];   // P[x_{t+3}], used at t+2

        // Broadcast pairs of h0, h1 (op_sel-foldable swizzles).
        // L1(t): b1 + Wih1 @ h0(t) + Whh1 @ h1(t-1), 4x 4-deep partials.
        v2f u[4], vv[4], w[4], z[4];
        #pragma unroll
        for (int p = 0; p < 4; ++p) {
            u[p]  = fma2(wih1pk[p * 8 + 0], h0p[0].xx, b1pk[p]);
            u[p]  = fma2(wih1pk[p * 8 + 1], h0p[0].yy, u[p]);
            u[p]  = fma2(wih1pk[p * 8 + 2], h0p[1].xx, u[p]);
            u[p]  = fma2(wih1pk[p * 8 + 3], h0p[1].yy, u[p]);
            vv[p] = mul2(wih1pk[p * 8 + 4], h0p[2].xx);
            vv[p] = fma2(wih1pk[p * 8 + 5], h0p[2].yy, vv[p]);
            vv[p] = fma2(wih1pk[p * 8 + 6], h0p[3].xx, vv[p]);
            vv[p] = fma2(wih1pk[p * 8 + 7], h0p[3].yy, vv[p]);
            w[p]  = mul2(whh1pk[p * 8 + 0], h1p[0].xx);
            w[p]  = fma2(whh1pk[p * 8 + 1], h1p[0].yy, w[p]);
            w[p]  = fma2(whh1pk[p * 8 + 2], h1p[1].xx, w[p]);
            w[p]  = fma2(whh1pk[p * 8 + 3], h1p[1].yy, w[p]);
            z[p]  = mul2(whh1pk[p * 8 + 4], h1p[2].xx);
            z[p]  = fma2(whh1pk[p * 8 + 5], h1p[2].yy, z[p]);
            z[p]  = fma2(whh1pk[p * 8 + 6], h1p[3].xx, z[p]);
            z[p]  = fma2(whh1pk[p * 8 + 7], h1p[3].yy, z[p]);
        }

        // L0(t+1): P[x_{t+1}] + Whh0 @ h0(t), 2x 4-deep partials.
        v2f m[4], n[4];
        #pragma unroll
        for (int p = 0; p < 4; ++p) {
            m[p] = fma2(whh0pk[p * 8 + 0], h0p[0].xx, pq[p]);
            m[p] = fma2(whh0pk[p * 8 + 1], h0p[0].yy, m[p]);
            m[p] = fma2(whh0pk[p * 8 + 2], h0p[1].xx, m[p]);
            m[p] = fma2(whh0pk[p * 8 + 3], h0p[1].yy, m[p]);
            n[p] = mul2(whh0pk[p * 8 + 4], h0p[2].xx);
            n[p] = fma2(whh0pk[p * 8 + 5], h0p[2].yy, n[p]);
            n[p] = fma2(whh0pk[p * 8 + 6], h0p[3].xx, n[p]);
            n[p] = fma2(whh0pk[p * 8 + 7], h0p[3].yy, n[p]);
        }

        #pragma unroll
        for (int p = 0; p < 4; ++p) h1p[p] = tanh2((u[p] + vv[p]) + (w[p] + z[p]));
        #pragma unroll
        for (int p = 0; p < 4; ++p) h0p[p] = tanh2(m[p] + n[p]);

        #pragma unroll
        for (int p = 0; p < 4; ++p) { pq[p] = nq[p]; nq[p] = rq[p]; }
        x3 = x4; x4 = x5v;
    }

    // ---- output loop: L1(t) + FC(t) + store; L0(t+1) ----
    for (int t = t_begin; t < t_end; ++t) {
        int tp = t + 5; if (tp > tmax) tp = tmax;
        int x5v = x[tp * B_LEN + b];
        v2f rq[4];
        #pragma unroll
        for (int p = 0; p < 4; ++p) rq[p] = Ppk[x3 * 4 + p];

        v2f u[4], vv[4], w[4], z[4];
        #pragma unroll
        for (int p = 0; p < 4; ++p) {
            u[p]  = fma2(wih1pk[p * 8 + 0], h0p[0].xx, b1pk[p]);
            u[p]  = fma2(wih1pk[p * 8 + 1], h0p[0].yy, u[p]);
            u[p]  = fma2(wih1pk[p * 8 + 2], h0p[1].xx, u[p]);
            u[p]  = fma2(wih1pk[p * 8 + 3], h0p[1].yy, u[p]);
            vv[p] = mul2(wih1pk[p * 8 + 4], h0p[2].xx);
            vv[p] = fma2(wih1pk[p * 8 + 5], h0p[2].yy, vv[p]);
            vv[p] = fma2(wih1pk[p * 8 + 6], h0p[3].xx, vv[p]);
            vv[p] = fma2(wih1pk[p * 8 + 7], h0p[3].yy, vv[p]);
            w[p]  = mul2(whh1pk[p * 8 + 0], h1p[0].xx);
            w[p]  = fma2(whh1pk[p * 8 + 1], h1p[0].yy, w[p]);
            w[p]  = fma2(whh1pk[p * 8 + 2], h1p[1].xx, w[p]);
            w[p]  = fma2(whh1pk[p * 8 + 3], h1p[1].yy, w[p]);
            z[p]  = mul2(whh1pk[p * 8 + 4], h1p[2].xx);
            z[p]  = fma2(whh1pk[p * 8 + 5], h1p[2].yy, z[p]);
            z[p]  = fma2(whh1pk[p * 8 + 6], h1p[3].xx, z[p]);
            z[p]  = fma2(whh1pk[p * 8 + 7], h1p[3].yy, z[p]);
        }

        v2f m[4], n[4];
        #pragma unroll
        for (int p = 0; p < 4; ++p) {
            m[p] = fma2(whh0pk[p * 8 + 0], h0p[0].xx, pq[p]);
            m[p] = fma2(whh0pk[p * 8 + 1], h0p[0].yy, m[p]);
            m[p] = fma2(whh0pk[p * 8 + 2], h0p[1].xx, m[p]);
            m[p] = fma2(whh0pk[p * 8 + 3], h0p[1].yy, m[p]);
            n[p] = mul2(whh0pk[p * 8 + 4], h0p[2].xx);
            n[p] = fma2(whh0pk[p * 8 + 5], h0p[2].yy, n[p]);
            n[p] = fma2(whh0pk[p * 8 + 6], h0p[3].xx, n[p]);
            n[p] = fma2(whh0pk[p * 8 + 7], h0p[3].yy, n[p]);
        }

        #pragma unroll
        for (int p = 0; p < 4; ++p) h1p[p] = tanh2((u[p] + vv[p]) + (w[p] + z[p]));
        #pragma unroll
        for (int p = 0; p < 4; ++p) h0p[p] = tanh2(m[p] + n[p]);

        // FC epilogue on h1(t): scalar v_fma with SGPR weight operand.
        float s0 = bf[0], s1 = bf[1], s2 = bf[2], s3 = bf[3];
        #pragma unroll
        for (int q = 0; q < 4; ++q) {
            s0 = __builtin_fmaf(wfc[0 * 8 + 2 * q], h1p[q].x, s0);
            s0 = __builtin_fmaf(wfc[0 * 8 + 2 * q + 1], h1p[q].y, s0);
            s1 = __builtin_fmaf(wfc[1 * 8 + 2 * q], h1p[q].x, s1);
            s1 = __builtin_fmaf(wfc[1 * 8 + 2 * q + 1], h1p[q].y, s1);
            s2 = __builtin_fmaf(wfc[2 * 8 + 2 * q], h1p[q].x, s2);
            s2 = __builtin_fmaf(wfc[2 * 8 + 2 * q + 1], h1p[q].y, s2);
            s3 = __builtin_fmaf(wfc[3 * 8 + 2 * q], h1p[q].x, s3);
            s3 = __builtin_fmaf(wfc[3 * 8 + 2 * q + 1], h1p[q].y, s3);
        }
        float4 o; o.x = s0; o.y = s1; o.z = s2; o.w = s3;
        outv[t * B_LEN + b] = o;   // 16B/lane, fully coalesced

        #pragma unroll
        for (int p = 0; p < 4; ++p) { pq[p] = nq[p]; nq[p] = rq[p]; }
        x3 = x4; x4 = x5v;
    }
}

extern "C" void kernel_launch(void* const* d_in, const int* in_sizes, int n_in,
                              void* d_out, int out_size, void* d_ws, size_t ws_size,
                              hipStream_t stream) {
    const int*   x    = (const int*)d_in[0];
    const float* emb  = (const float*)d_in[1];
    const float* Wih0 = (const float*)d_in[2];
    const float* Whh0 = (const float*)d_in[3];
    const float* bih0 = (const float*)d_in[4];
    const float* bhh0 = (const float*)d_in[5];
    const float* Wih1 = (const float*)d_in[6];
    const float* Whh1 = (const float*)d_in[7];
    const float* bih1 = (const float*)d_in[8];
    const float* bhh1 = (const float*)d_in[9];
    const float* Wfc  = (const float*)d_in[10];
    const float* bfc  = (const float*)d_in[11];
    float* out = (float*)d_out;

    dim3 grid((B_LEN / 64) * NCHUNK);   // 1024 blocks x 64 threads = 1 wave/SIMD
    dim3 block(64);
    hipLaunchKernelGGL(rnn_fused, grid, block, 0, stream,
                       x, emb, Wih0, Whh0, bih0, bhh0,
                       Wih1, Whh1, bih1, bhh1, Wfc, bfc, out);
}